// Round 3
// baseline (268.187 us; speedup 1.0000x reference)
//
#include <hip/hip_runtime.h>
#include <hip/hip_bf16.h>

// B=32, CQ=256, CC=3, COUT=256, H=W=32, HW=1024, INTER=128
//
// Math (verified rounds 0-2, absmax 0.031):
//   scores[i,j] = a[:,i]·ctx[:,j] + c_i (softmax-invariant const dropped)
//     a = M·Q + m0, M = Wk^T Wq (3x256)
//   fused = Wp·Q + G·cp + g0;  G = Wp·Wv (256x3), cp[t,i] = sum_j ctx[t,j]P[i,j]
//   resize 224->32 half-pixel = exact gather at (7y+3, 7x+3).
//
// Workspace (float offsets):
#define WS_M     0        // M[3][256], m0[3] at 768
#define WS_G4    1024     // G4[o] = {G0,G1,G2,g0}
#define WS_BSUM  2048     // [32]
#define WS_BSSQ  2080     // [32]
#define WS_WPB   2112     // Wp bf16 [256][256]
#define WS_CTX4  34880    // ctx4[b][j] = {c0,c1,c2,0}
#define WS_A4    165952   // a4[b][i]
#define WS_CP4   297024   // cp4[b][i]
#define WS_QT    428096   // Qt bf16 [b][i][k]

typedef __attribute__((ext_vector_type(8))) short short8;
typedef __attribute__((ext_vector_type(4))) float floatx4;

__device__ inline unsigned short f2bf(float x) {
    unsigned u = __float_as_uint(x);
    return (unsigned short)((u + 0x7FFFu + ((u >> 16) & 1u)) >> 16);
}

// ---------- K0: weight precompute (tiny) + zero the stat accumulators ----------
__global__ __launch_bounds__(256) void sca_pre(
    const float* __restrict__ Wq, const float* __restrict__ bq,
    const float* __restrict__ Wk, const float* __restrict__ bk,
    const float* __restrict__ Wv, const float* __restrict__ bv,
    const float* __restrict__ Wp, const float* __restrict__ bp,
    float* __restrict__ ws)
{
    int tid = threadIdx.x;
    int blk = blockIdx.x;
    if (blk == 0) {
        float m0v = 0.f, m1v = 0.f, m2v = 0.f;
        for (int c = 0; c < 128; ++c) {
            float q = Wq[c * 256 + tid];
            m0v = fmaf(Wk[c * 3 + 0], q, m0v);
            m1v = fmaf(Wk[c * 3 + 1], q, m1v);
            m2v = fmaf(Wk[c * 3 + 2], q, m2v);
        }
        ws[WS_M + 0   + tid] = m0v;
        ws[WS_M + 256 + tid] = m1v;
        ws[WS_M + 512 + tid] = m2v;
        if (tid < 3) {
            float s = 0.f;
            for (int c = 0; c < 128; ++c) s = fmaf(Wk[c * 3 + tid], bq[c], s);
            ws[WS_M + 768 + tid] = s;
        }
        if (tid < 64) ws[WS_BSUM + tid] = 0.f;   // bsum[32]+bssq[32] contiguous
    } else if (blk == 1) {
        float g0 = 0.f, g1 = 0.f, g2 = 0.f, gb = 0.f;
        const float4* wr4 = (const float4*)(Wp + tid * 256);
        for (int c4 = 0; c4 < 64; ++c4) {
            float4 w = wr4[c4];
            int c = c4 * 4;
            g0 = fmaf(w.x, Wv[(c+0)*3+0], g0); g1 = fmaf(w.x, Wv[(c+0)*3+1], g1); g2 = fmaf(w.x, Wv[(c+0)*3+2], g2); gb = fmaf(w.x, bv[c+0], gb);
            g0 = fmaf(w.y, Wv[(c+1)*3+0], g0); g1 = fmaf(w.y, Wv[(c+1)*3+1], g1); g2 = fmaf(w.y, Wv[(c+1)*3+2], g2); gb = fmaf(w.y, bv[c+1], gb);
            g0 = fmaf(w.z, Wv[(c+2)*3+0], g0); g1 = fmaf(w.z, Wv[(c+2)*3+1], g1); g2 = fmaf(w.z, Wv[(c+2)*3+2], g2); gb = fmaf(w.z, bv[c+2], gb);
            g0 = fmaf(w.w, Wv[(c+3)*3+0], g0); g1 = fmaf(w.w, Wv[(c+3)*3+1], g1); g2 = fmaf(w.w, Wv[(c+3)*3+2], g2); gb = fmaf(w.w, bv[c+3], gb);
        }
        ((float4*)(ws + WS_G4))[tid] = make_float4(g0, g1, g2, gb + bp[tid]);
    } else {
        // convert Wp -> bf16 row-major, blocks 2..33
        int idx = (blk - 2) * 2048 + tid * 8;
        const float4* s = (const float4*)(Wp + idx);
        float4 x0 = s[0], x1 = s[1];
        uint4 o;
        o.x = (unsigned)f2bf(x0.x) | ((unsigned)f2bf(x0.y) << 16);
        o.y = (unsigned)f2bf(x0.z) | ((unsigned)f2bf(x0.w) << 16);
        o.z = (unsigned)f2bf(x1.x) | ((unsigned)f2bf(x1.y) << 16);
        o.w = (unsigned)f2bf(x1.z) | ((unsigned)f2bf(x1.w) << 16);
        ((uint4*)((unsigned short*)(ws + WS_WPB)))[idx >> 3] = o;
    }
}

// ---------- K1: blocks 0..511: a = M@Q + m0 and Qt = bf16(Q)^T (coalesced via
//              XOR-swizzled LDS transpose). blocks 512..639: ctx resize-gather. ----------
__global__ __launch_bounds__(256) void sca_conv(const float* __restrict__ Q,
                                                const float* __restrict__ ctxin,
                                                float* __restrict__ ws)
{
    int tid = threadIdx.x;
    int blk = blockIdx.x;
    if (blk >= 512) {
        // gather: one (b,j) per thread, 3 scattered loads, float4 store
        int e = ((blk - 512) << 8) | tid;
        int b = e >> 10, j = e & 1023;
        int y = j >> 5, x = j & 31;
        const float* src = ctxin + (size_t)b * 150528 + (7 * y + 3) * 224 + (7 * x + 3);
        ((float4*)(ws + WS_CTX4))[e] =
            make_float4(src[0], src[50176], src[100352], 0.f);
        return;
    }
    __shared__ float Ms[771];
    __shared__ float red[4][3][64];
    __shared__ unsigned T[8192];           // 64 rows x 128 words (bf16 pairs)
    for (int idx = tid; idx < 771; idx += 256) Ms[idx] = ws[WS_M + idx];
    __syncthreads();
    int b  = blk >> 4;
    int i0 = (blk & 15) << 6;
    int il = tid & 63, cs = tid >> 6;      // 4 c-slices x 64 i-lanes
    const float* Qp = Q + ((size_t)b << 18) + ((size_t)cs << 16) + i0 + il;
    int cb = cs << 6;
    float a0 = 0.f, a1 = 0.f, a2 = 0.f;
    unsigned qp[32];
#pragma unroll 8
    for (int cc = 0; cc < 64; ++cc) {
        float qv = Qp[(size_t)cc << 10];
        a0 = fmaf(Ms[cb + cc],       qv, a0);
        a1 = fmaf(Ms[256 + cb + cc], qv, a1);
        a2 = fmaf(Ms[512 + cb + cc], qv, a2);
        unsigned h = f2bf(qv);
        if (cc & 1) qp[cc >> 1] |= (h << 16); else qp[cc >> 1] = h;
    }
    // stash into LDS, 16B-group XOR swizzle: row il, logical group g -> g^(il&31)
#pragma unroll
    for (int w4 = 0; w4 < 8; ++w4) {
        int pg = ((cs << 3) + w4) ^ (il & 31);
        *(uint4*)&T[(il << 7) + (pg << 2)] =
            make_uint4(qp[w4*4], qp[w4*4+1], qp[w4*4+2], qp[w4*4+3]);
    }
    red[cs][0][il] = a0; red[cs][1][il] = a1; red[cs][2][il] = a2;
    __syncthreads();
    // coalesced Qt store: tile = 64 rows x 128 words, 16B per thread per iter
    uint4* qdst = (uint4*)((unsigned short*)(ws + WS_QT) + (((size_t)(b * 1024 + i0)) << 8));
#pragma unroll
    for (int iter = 0; iter < 8; ++iter) {
        int f = (iter << 10) + (tid << 2);          // word index in tile
        int i = f >> 7, lg = (f >> 2) & 31;
        int pg = lg ^ (i & 31);
        qdst[(iter << 8) + tid] = *(const uint4*)&T[(i << 7) + (pg << 2)];
    }
    if (tid < 64) {
        float r0 = red[0][0][tid] + red[1][0][tid] + red[2][0][tid] + red[3][0][tid];
        float r1 = red[0][1][tid] + red[1][1][tid] + red[2][1][tid] + red[3][1][tid];
        float r2 = red[0][2][tid] + red[1][2][tid] + red[2][2][tid] + red[3][2][tid];
        ((float4*)(ws + WS_A4))[b * 1024 + i0 + tid] =
            make_float4(r0 + Ms[768], r1 + Ms[769], r2 + Ms[770], 0.f);
    }
}

// ---------- K2: single-pass softmax (analytic shift) + cp accumulation ----------
__global__ __launch_bounds__(256) void sca_attn(float* __restrict__ ws)
{
    __shared__ float4 cs[1024];
    int tid = threadIdx.x;
    int b  = blockIdx.x >> 4;
    int i0 = (blockIdx.x & 15) << 6;
    const float4* cb = (const float4*)(ws + WS_CTX4) + b * 1024;
    for (int idx = tid; idx < 1024; idx += 256) cs[idx] = cb[idx];
    __syncthreads();
    int il = tid >> 2, sl = tid & 3;
    int i = i0 + il;
    float4 a = ((const float4*)(ws + WS_A4))[b * 1024 + i];
    float sh = 6.0f * (fabsf(a.x) + fabsf(a.y) + fabsf(a.z));
    float d = 0.f, s0 = 0.f, s1 = 0.f, s2 = 0.f;
#pragma unroll 4
    for (int jj = 0; jj < 256; ++jj) {
        float4 c = cs[(jj << 2) + sl];
        float sc = fmaf(a.x, c.x, fmaf(a.y, c.y, a.z * c.z));
        float e = __expf(sc - sh);
        d += e;
        s0 = fmaf(e, c.x, s0);
        s1 = fmaf(e, c.y, s1);
        s2 = fmaf(e, c.z, s2);
    }
    d  += __shfl_xor(d, 1);  d  += __shfl_xor(d, 2);
    s0 += __shfl_xor(s0, 1); s0 += __shfl_xor(s0, 2);
    s1 += __shfl_xor(s1, 1); s1 += __shfl_xor(s1, 2);
    s2 += __shfl_xor(s2, 1); s2 += __shfl_xor(s2, 2);
    if (sl == 0) {
        float inv = 1.0f / d;
        ((float4*)(ws + WS_CP4))[b * 1024 + i] =
            make_float4(s0 * inv, s1 * inv, s2 * inv, 0.f);
    }
}

// ---------- K3: MFMA GEMM out = Wp@Q + G@cp + g0, register double-buffered ----------
// 1024 blocks = b x 2 o-halves x 16 i-tiles(64). 4 waves: (wo,wi), wave = 64o x 32i.
__global__ __launch_bounds__(256) void sca_gemm(float* __restrict__ ws,
                                                float* __restrict__ out)
{
    int tid = threadIdx.x;
    int blk = blockIdx.x;
    int it = blk & 15;
    int ot = (blk >> 4) & 1;
    int b  = blk >> 5;
    int w  = tid >> 6, lane = tid & 63;
    int wo = w >> 1, wi = w & 1;
    int m = lane & 15, quad = lane >> 4;
    int o_base = ot * 128 + wo * 64;
    int i_base = it * 64 + wi * 32;

    const unsigned short* Wpb = (const unsigned short*)(ws + WS_WPB);
    const unsigned short* Qt  = (const unsigned short*)(ws + WS_QT);
    const unsigned short* Ap = Wpb + ((size_t)(o_base + m) << 8) + (quad << 3);
    const unsigned short* Bp = Qt + ((size_t)(b * 1024 + i_base + m) << 8) + (quad << 3);

    short8 af[2][4], bf[2][2];
#pragma unroll
    for (int t = 0; t < 4; ++t) af[0][t] = *(const short8*)(Ap + (t << 12));
#pragma unroll
    for (int t = 0; t < 2; ++t) bf[0][t] = *(const short8*)(Bp + (t << 12));

    floatx4 acc[4][2] = {};
#pragma unroll
    for (int ks = 0; ks < 8; ++ks) {
        int cur = ks & 1, nxt = cur ^ 1;
        if (ks < 7) {
#pragma unroll
            for (int t = 0; t < 4; ++t)
                af[nxt][t] = *(const short8*)(Ap + (t << 12) + ((ks + 1) << 5));
#pragma unroll
            for (int t = 0; t < 2; ++t)
                bf[nxt][t] = *(const short8*)(Bp + (t << 12) + ((ks + 1) << 5));
        }
#pragma unroll
        for (int to = 0; to < 4; ++to)
#pragma unroll
            for (int ti = 0; ti < 2; ++ti)
                acc[to][ti] = __builtin_amdgcn_mfma_f32_16x16x32_bf16(
                    af[cur][to], bf[cur][ti], acc[to][ti], 0, 0, 0);
    }

    // epilogue: rank-3 correction + bias, store, GroupNorm partial stats
    const floatx4* G4  = (const floatx4*)(ws + WS_G4);
    const floatx4* cp4 = (const floatx4*)(ws + WS_CP4) + b * 1024;
    floatx4 cpv[2];
#pragma unroll
    for (int ti = 0; ti < 2; ++ti) cpv[ti] = cp4[i_base + ti * 16 + m];
    float lsum = 0.f, lssq = 0.f;
#pragma unroll
    for (int to = 0; to < 4; ++to) {
#pragma unroll
        for (int r = 0; r < 4; ++r) {
            int o = o_base + to * 16 + quad * 4 + r;
            floatx4 g = G4[o];
            float* orow = out + (((size_t)(b * 256 + o)) << 10) + i_base + m;
#pragma unroll
            for (int ti = 0; ti < 2; ++ti) {
                float v = acc[to][ti][r]
                        + g[0] * cpv[ti][0] + g[1] * cpv[ti][1] + g[2] * cpv[ti][2] + g[3];
                orow[ti * 16] = v;
                lsum += v; lssq = fmaf(v, v, lssq);
            }
        }
    }
#pragma unroll
    for (int off = 32; off > 0; off >>= 1) {
        lsum += __shfl_down(lsum, off);
        lssq += __shfl_down(lssq, off);
    }
    if (lane == 0) {
        atomicAdd(ws + WS_BSUM + b, lsum);
        atomicAdd(ws + WS_BSSQ + b, lssq);
    }
}

// ---------- K4: GroupNorm(1 group) normalize in place ----------
__global__ __launch_bounds__(256) void sca_norm(float* __restrict__ out,
                                                const float* __restrict__ ws,
                                                const float* __restrict__ gamma,
                                                const float* __restrict__ beta)
{
    size_t idx = (size_t)blockIdx.x * 256 + threadIdx.x;  // float4 index
    float4 v = ((const float4*)out)[idx];
    size_t base = idx << 2;
    int b = (int)(base >> 18);
    int o = (int)((base >> 10) & 255);
    const float inv_n = 1.0f / 262144.0f;
    float mean = ws[WS_BSUM + b] * inv_n;
    float var  = fmaf(ws[WS_BSSQ + b], inv_n, -mean * mean);
    float rs = rsqrtf(var + 1e-5f);
    float ga = gamma[o] * rs;
    float be = fmaf(-mean, ga, beta[o]);
    v.x = fmaf(v.x, ga, be);
    v.y = fmaf(v.y, ga, be);
    v.z = fmaf(v.z, ga, be);
    v.w = fmaf(v.w, ga, be);
    ((float4*)out)[idx] = v;
}

extern "C" void kernel_launch(void* const* d_in, const int* in_sizes, int n_in,
                              void* d_out, int out_size, void* d_ws, size_t ws_size,
                              hipStream_t stream)
{
    const float* Q     = (const float*)d_in[0];
    const float* ctxf  = (const float*)d_in[1];
    const float* Wq    = (const float*)d_in[2];
    const float* bq    = (const float*)d_in[3];
    const float* Wk    = (const float*)d_in[4];
    const float* bk    = (const float*)d_in[5];
    const float* Wv    = (const float*)d_in[6];
    const float* bv    = (const float*)d_in[7];
    const float* Wp    = (const float*)d_in[8];
    const float* bp    = (const float*)d_in[9];
    const float* gamma = (const float*)d_in[10];
    const float* beta  = (const float*)d_in[11];
    float* ws  = (float*)d_ws;
    float* out = (float*)d_out;

    sca_pre <<<34,   256, 0, stream>>>(Wq, bq, Wk, bk, Wv, bv, Wp, bp, ws);
    sca_conv<<<640,  256, 0, stream>>>(Q, ctxf, ws);
    sca_attn<<<512,  256, 0, stream>>>(ws);
    sca_gemm<<<1024, 256, 0, stream>>>(ws, out);
    sca_norm<<<8192, 256, 0, stream>>>(out, ws, gamma, beta);
}